// Round 2
// baseline (560.875 us; speedup 1.0000x reference)
//
#include <hip/hip_runtime.h>
#include <hip/hip_bf16.h>

#define T_LEN   100000   // time samples
#define C_SEL   256      // selected channels
#define C_IN    512      // input channel stride
#define KLOW    12000    // low-pass taps
#define B1      50       // low-pass decimation block
#define NB1     2000     // T_LEN / B1
#define ND1     2001     // low nodes: t = 50*jd, jd = 0..2000
#define NW1     241      // block-averaged low weights
#define ND2E    5003     // out nodes: t = 20*(jo-1), jo = 0..5002 (one extra each side for Catmull-Rom)
#define WH_OFF  5500     // gauss_high truncation start (center 6000 ± 500)
#define KH      1001     // truncated high-pass taps
#define NR2     8        // decimated outputs per block (one node-group)
#define NGB     626      // ceil(5003 / 8) node-group blocks
#define MLEN    5000     // decimated length per phase (T_LEN/20)
#define PLANE   (MLEN*C_SEL)   // floats per phase plane of x_pack

typedef __attribute__((ext_vector_type(4))) float f32x4;

// kA: fused prep + block sums + phase-major pack.
//  blocks 0..NB1-1: S[jb][c] = 50-sample block sums of selected channels,
//                   AND x_pack[t%20][t/20][c] = x[t][sel[c]]  (phase-major pack,
//                   so kC's per-phase windows become contiguous 1KB rows).
//  block NB1: W1 (block-averaged low weights), musum=0, cwh = prefix of truncated high kernel.
__global__ __launch_bounds__(256) void kA_prep(const float* __restrict__ x,
                                               const int* __restrict__ sel,
                                               const float* __restrict__ wlow,
                                               const float* __restrict__ whigh,
                                               float* __restrict__ S,
                                               float* __restrict__ W1,
                                               float* __restrict__ musum,
                                               float* __restrict__ cwh,
                                               float* __restrict__ xp){
  if (blockIdx.x < NB1){
    int jb = blockIdx.x, c = threadIdx.x;
    int sc = sel[c];
    const float* p = x + (size_t)jb*(B1*C_IN) + sc;
    int t0 = jb*B1;
    float s = 0.f;
    #pragma unroll
    for (int i = 0; i < B1; ++i){
      float v = p[(size_t)i*C_IN];
      s += v;
      int t = t0 + i;
      xp[(size_t)(t % 20)*PLANE + (size_t)(t / 20)*C_SEL + c] = v;
    }
    S[jb*C_SEL + c] = s;
  } else {
    int m1 = threadIdx.x;
    if (m1 == 0){
      musum[0] = 0.f;
      float run = 0.f;
      cwh[0] = 0.f;
      for (int j = 0; j < KH; ++j){ run += whigh[WH_OFF + j]; cwh[j+1] = run; }
    }
    if (m1 < NW1){
      float s = 0.f;
      int kbase = 50*m1 - 1;
      for (int off = 0; off < 50; ++off){
        int k = kbase + off;
        if (k >= 0 && k < KLOW) s += wlow[k];
      }
      W1[m1] = s * (1.0f/50.0f);   // block MEAN weight × block SUM of x
    }
  }
}

// kB: decimated low-pass: lowd[jd][c] = sum_m1 W1[m1]*S[jd+m1-120][c];
// fused: trapezoid-weighted sum for mean(low_full) -> musum.
__global__ __launch_bounds__(256) void kB_lowd(const float* __restrict__ S,
                                               const float* __restrict__ W1,
                                               float* __restrict__ lowd,
                                               float* __restrict__ musum){
  __shared__ float w1s[NW1];
  __shared__ float red[256];
  int jd = blockIdx.x, c = threadIdx.x;
  if (c < NW1) w1s[c] = W1[c];
  __syncthreads();
  float acc = 0.f;
  for (int m1 = 0; m1 < NW1; ++m1){
    int jb = jd + m1 - 120;
    if (jb >= 0 && jb < NB1) acc += w1s[m1]*S[jb*C_SEL + c];
  }
  lowd[jd*C_SEL + c] = acc;
  red[c] = acc;
  __syncthreads();
  for (int s2 = 128; s2 > 0; s2 >>= 1){
    if (c < s2) red[c] += red[c + s2];
    __syncthreads();
  }
  if (c == 0){
    // sum_t lerp(low)[t] = 25.5*L[0] + 50*L[1..1999] + 24.5*L[2000]
    float ew = (jd == 0) ? 25.5f : ((jd == ND1-1) ? 24.5f : 50.f);
    atomicAdd(musum, ew*red[0]);
  }
}

// kC core: for node jo, conv[jo] = sum_{j=0..1000} whT[j] * xsel[20*(jo-1)+j-499].
// Phase decomposition t = 20m+p: j = 20d+p+499 with d = m-(jo-1); u = d+25 in [0,50],
// tap wp[u] = whT[20u+p-1] = whs[20u+p]  (whs is the +1-shifted zero-padded kernel).
// Per wave (5 phases): window m in [jo0-26, jo0+31] = 58 CONTIGUOUS rows of the
// phase plane -> lane loads float4 (4 channels), 64 lanes = full 1KB row/instr.
template<bool FAST>
__device__ __forceinline__ void conv_core2(const float* __restrict__ xp,
                                           const float* __restrict__ whs,
                                           int jo0, int pg, int lane, f32x4* acc){
  #pragma unroll 1
  for (int pi = 0; pi < 5; ++pi){
    int p = pg*5 + pi;
    float wp[51];
    #pragma unroll
    for (int u = 0; u < 51; ++u) wp[u] = whs[20*u + p];
    const float* base = xp + (size_t)p*PLANE + (size_t)(jo0 - 26)*C_SEL + 4*lane;
    #pragma unroll
    for (int q = 0; q < 58; ++q){
      f32x4 v;
      if (FAST){
        v = *reinterpret_cast<const f32x4*>(base + (size_t)q*C_SEL);
      } else {
        int m = jo0 - 26 + q;
        if (m >= 0 && m < MLEN) v = *reinterpret_cast<const f32x4*>(base + (size_t)q*C_SEL);
        else                    v = f32x4{0.f, 0.f, 0.f, 0.f};
      }
      #pragma unroll
      for (int r = 0; r < NR2; ++r){
        int u = q - r;
        if (u >= 0 && u <= 50) acc[r] += wp[u]*v;   // u compile-time const per (q,r)
      }
    }
  }
}

// kC: outd[jo] = conv(xp)[jo] + (mu - low(t_jo)) * s(t_jo)
// Block = 256 thr = 4 waves = 4 phase-groups x ONE 8-node group x ALL 256 channels.
// Cross-wave sum of the 4 phase partials via LDS (f32x4 rows, conflict-benign).
__global__ __launch_bounds__(256, 3) void kC_conv(const float* __restrict__ xp,
                                                  const float* __restrict__ whigh,
                                                  const float* __restrict__ cwh,
                                                  const float* __restrict__ lowd,
                                                  const float* __restrict__ musum,
                                                  float* __restrict__ outd){
  __shared__ float whs[1024];
  __shared__ f32x4 red[4][NR2][64];
  int tid = threadIdx.x;
  for (int i = tid; i < 1024; i += 256){
    int j = i - 1;                     // whs[i] = whT[i-1], zero-padded
    whs[i] = (j >= 0 && j < KH) ? whigh[WH_OFF + j] : 0.f;
  }
  __syncthreads();
  int lane = tid & 63;
  int pg   = tid >> 6;                 // phase-group = wave id (5 phases each)
  int jo0  = blockIdx.x * NR2;
  f32x4 acc[NR2];
  #pragma unroll
  for (int r = 0; r < NR2; ++r) acc[r] = f32x4{0.f, 0.f, 0.f, 0.f};
  if (jo0 >= 26 && jo0 + 31 < MLEN) conv_core2<true >(xp, whs, jo0, pg, lane, acc);
  else                              conv_core2<false>(xp, whs, jo0, pg, lane, acc);
  #pragma unroll
  for (int r = 0; r < NR2; ++r) red[pg][r][lane] = acc[r];
  __syncthreads();

  // epilogue: 32 threads per node row; each thread finishes 2 float4 (8 channels)
  float mu = musum[0] * (1.0f/((float)T_LEN*(float)C_SEL));
  int r  = tid >> 5;
  int jo = jo0 + r;
  if (jo < ND2E){
    int tn = 20*(jo - 1);
    int jmin = 499 - tn;             if (jmin < 0) jmin = 0;
    int jmax = T_LEN - 1 + 499 - tn; if (jmax > 1000) jmax = 1000;
    float s = cwh[jmax + 1] - cwh[jmin];
    int tc = tn < 0 ? 0 : (tn > T_LEN-1 ? T_LEN-1 : tn);
    int jd = tc/50, rr = tc - 50*jd;
    float fr = rr*(1.f/50.f);
    #pragma unroll
    for (int k = 0; k < 2; ++k){
      int j = ((tid & 31) << 1) + k;   // float4 column 0..63
      f32x4 a = red[0][r][j] + red[1][r][j] + red[2][r][j] + red[3][r][j];
      f32x4 l0 = *reinterpret_cast<const f32x4*>(lowd + (size_t)jd*C_SEL + 4*j);
      f32x4 l1 = *reinterpret_cast<const f32x4*>(lowd + (size_t)(jd+1)*C_SEL + 4*j);
      f32x4 lo = l0 + (l1 - l0)*fr;
      f32x4 o  = a + (mu - lo)*s;
      *reinterpret_cast<f32x4*>(outd + (size_t)jo*C_SEL + 4*j) = o;
    }
  }
}

// kD: Catmull-Rom interpolation of the decimated output back to full rate.
__global__ __launch_bounds__(256) void kD_interp(const float* __restrict__ outd,
                                                 float* __restrict__ out){
  int c = threadIdx.x;
  int t0 = blockIdx.x*8;
  #pragma unroll
  for (int i = 0; i < 8; ++i){
    int t = t0 + i;
    int jo = t/20, rr = t - jo*20;
    float a = rr*(1.f/20.f);
    float p0 = outd[(jo    )*C_SEL + c];
    float p1 = outd[(jo + 1)*C_SEL + c];   // node at t = 20*jo
    float p2 = outd[(jo + 2)*C_SEL + c];   // node at t = 20*(jo+1)
    float p3 = outd[(jo + 3)*C_SEL + c];
    float m = p1 + 0.5f*a*((p2 - p0)
            + a*((2.f*p0 - 5.f*p1 + 4.f*p2 - p3)
            + a*(3.f*(p1 - p2) + p3 - p0)));
    out[(size_t)t*C_SEL + c] = m;
  }
}

extern "C" void kernel_launch(void* const* d_in, const int* in_sizes, int n_in,
                              void* d_out, int out_size, void* d_ws, size_t ws_size,
                              hipStream_t stream){
  const float* firings = (const float*)d_in[0];
  const float* glow    = (const float*)d_in[1];
  const float* ghigh   = (const float*)d_in[2];
  const int*   sel     = (const int*)d_in[3];
  float* out = (float*)d_out;
  float* ws  = (float*)d_ws;

  // workspace layout (floats): ~112 MB total (poison fill shows ws ~ 819 MB)
  float* W1    = ws;                 // 256
  float* musum = ws + 256;           // 64 (1 used)
  float* cwh   = ws + 320;           // 1002 (pad to 1728)
  float* S     = ws + 2048;          // 2000*256 = 512000   (ends 514048)
  float* lowd  = ws + 514048;        // 2001*256 = 512256   (ends 1026304)
  float* outd  = ws + 1026304;       // 5003*256 = 1280768  (ends 2307072)
  float* xp    = ws + 2307072;       // 20*5000*256 = 25600000 (ends 27907072)

  hipLaunchKernelGGL(kA_prep,  dim3(NB1+1),   dim3(256), 0, stream,
                     firings, sel, glow, ghigh, S, W1, musum, cwh, xp);
  hipLaunchKernelGGL(kB_lowd,  dim3(ND1),     dim3(256), 0, stream, S, W1, lowd, musum);
  hipLaunchKernelGGL(kC_conv,  dim3(NGB),     dim3(256), 0, stream,
                     xp, ghigh, cwh, lowd, musum, outd);
  hipLaunchKernelGGL(kD_interp,dim3(T_LEN/8), dim3(256), 0, stream, outd, out);
}

// Round 3
// 481.938 us; speedup vs baseline: 1.1638x; 1.1638x over previous
//
#include <hip/hip_runtime.h>
#include <hip/hip_bf16.h>

#define T_LEN   100000   // time samples
#define C_SEL   256      // selected channels
#define C_IN    512      // input channel stride
#define KLOW    12000    // low-pass taps
#define B1      50       // low-pass decimation block
#define NB1     2000     // T_LEN / B1
#define ND1     2001     // low nodes: t = 50*jd, jd = 0..2000
#define NW1     241      // block-averaged low weights
#define ND2E    5003     // out nodes: t = 20*(jo-1), jo = 0..5002 (one extra each side for Catmull-Rom)
#define WH_OFF  5500     // gauss_high truncation start (center 6000 ± 500)
#define KH      1001     // truncated high-pass taps
#define NR2     8        // decimated outputs per node-group
#define NGX     626      // ceil(5003 / 8) node-group blocks
#define NPG     5        // phase-groups (4 phases each, one per wave)
#define NWG     (NGX*NPG) // 3130 kC blocks
#define MLEN    5000     // decimated length per phase (T_LEN/20)

typedef __attribute__((ext_vector_type(4))) float f32x4;

// kA: fused prep + block sums (vectorized, no packing).
//  blocks 0..NB1-1: S[jb][c] = 50-sample block sums of selected channels.
//    sel is arange(256) in practice -> channels are the contiguous first 1KB
//    of each 2KB row: float4 loads, full-row coalescing. Runtime-checked with
//    a gather fallback for safety.
//  block NB1: W1 (block-averaged low weights), musum=0, cwh = prefix of truncated high kernel.
__global__ __launch_bounds__(256) void kA_prep(const float* __restrict__ x,
                                               const int* __restrict__ sel,
                                               const float* __restrict__ wlow,
                                               const float* __restrict__ whigh,
                                               float* __restrict__ S,
                                               float* __restrict__ W1,
                                               float* __restrict__ musum,
                                               float* __restrict__ cwh){
  if (blockIdx.x < NB1){
    __shared__ f32x4 red[4][64];
    int jb = blockIdx.x;
    int tid = threadIdx.x;
    int c4 = tid & 63;          // float4 column (4 channels)
    int w  = tid >> 6;          // wave id: rows i = w, w+4, ...
    int s0 = sel[4*c4+0], s1 = sel[4*c4+1], s2 = sel[4*c4+2], s3 = sel[4*c4+3];
    bool contig = (s0 == 4*c4) && (s1 == 4*c4+1) && (s2 == 4*c4+2) && (s3 == 4*c4+3);
    bool allc = __all(contig);
    f32x4 acc = {0.f, 0.f, 0.f, 0.f};
    const float* rowb = x + (size_t)jb*(B1*C_IN);
    if (allc){
      for (int i = w; i < B1; i += 4)
        acc += *reinterpret_cast<const f32x4*>(rowb + (size_t)i*C_IN + 4*c4);
    } else {
      for (int i = w; i < B1; i += 4){
        const float* r = rowb + (size_t)i*C_IN;
        f32x4 v = { r[s0], r[s1], r[s2], r[s3] };
        acc += v;
      }
    }
    red[w][c4] = acc;
    __syncthreads();
    if (tid < 64){
      f32x4 s = red[0][tid] + red[1][tid] + red[2][tid] + red[3][tid];
      *reinterpret_cast<f32x4*>(S + (size_t)jb*C_SEL + 4*tid) = s;
    }
  } else {
    int m1 = threadIdx.x;
    if (m1 == 0){
      musum[0] = 0.f;
      float run = 0.f;
      cwh[0] = 0.f;
      for (int j = 0; j < KH; ++j){ run += whigh[WH_OFF + j]; cwh[j+1] = run; }
    }
    if (m1 < NW1){
      float s = 0.f;
      int kbase = 50*m1 - 1;
      for (int off = 0; off < 50; ++off){
        int k = kbase + off;
        if (k >= 0 && k < KLOW) s += wlow[k];
      }
      W1[m1] = s * (1.0f/50.0f);   // block MEAN weight × block SUM of x
    }
  }
}

// kB: decimated low-pass: lowd[jd][c] = sum_m1 W1[m1]*S[jd+m1-120][c];
// fused: trapezoid-weighted sum for mean(low_full) -> musum.
__global__ __launch_bounds__(256) void kB_lowd(const float* __restrict__ S,
                                               const float* __restrict__ W1,
                                               float* __restrict__ lowd,
                                               float* __restrict__ musum){
  __shared__ float w1s[NW1];
  __shared__ float red[256];
  int jd = blockIdx.x, c = threadIdx.x;
  if (c < NW1) w1s[c] = W1[c];
  __syncthreads();
  float acc = 0.f;
  for (int m1 = 0; m1 < NW1; ++m1){
    int jb = jd + m1 - 120;
    if (jb >= 0 && jb < NB1) acc += w1s[m1]*S[jb*C_SEL + c];
  }
  lowd[jd*C_SEL + c] = acc;
  red[c] = acc;
  __syncthreads();
  for (int s2 = 128; s2 > 0; s2 >>= 1){
    if (c < s2) red[c] += red[c + s2];
    __syncthreads();
  }
  if (c == 0){
    // sum_t lerp(low)[t] = 25.5*L[0] + 50*L[1..1999] + 24.5*L[2000]
    float ew = (jd == 0) ? 25.5f : ((jd == ND1-1) ? 24.5f : 50.f);
    atomicAdd(musum, ew*red[0]);
  }
}

// kC core: for node jo, conv[jo] = sum_{j=0..1000} whT[j] * xsel[20*(jo-1)+j-499].
// Phase decomposition t = 20m+p: tap index j = 20u+p-1, u = m-jo+26 in [0,50];
// whs is the +1-shifted zero-padded kernel so wp[u] = whs[20u+p].
// ONE phase per wave; window m in [jo0-26, jo0+31] = 58 rows; lane loads float4
// (4 contiguous channels) directly from firings -> 64 lanes = 1KB/row, coalesced.
template<bool FAST>
__device__ __forceinline__ void conv_core3(const float* __restrict__ x,
                                           const float* wp,
                                           int m0, int p, int lane,
                                           int s0, int s1, int s2, int s3,
                                           bool allc, f32x4* acc){
  if (FAST){
    const float* base = x + (size_t)(20*m0 + p)*C_IN + 4*lane;
    #pragma unroll
    for (int q = 0; q < 58; ++q){
      f32x4 v = *reinterpret_cast<const f32x4*>(base + (size_t)q*(20*C_IN));
      #pragma unroll
      for (int r = 0; r < NR2; ++r){
        int u = q - r;
        if (u >= 0 && u <= 50) acc[r] += wp[u]*v;   // u compile-time const per (q,r)
      }
    }
  } else {
    #pragma unroll 1
    for (int q = 0; q < 58; ++q){
      int m = m0 + q;
      f32x4 v = {0.f, 0.f, 0.f, 0.f};
      if (m >= 0 && m < MLEN){
        const float* row = x + (size_t)(20*m + p)*C_IN;
        if (allc) v = *reinterpret_cast<const f32x4*>(row + 4*lane);
        else      v = f32x4{ row[s0], row[s1], row[s2], row[s3] };
      }
      #pragma unroll
      for (int r = 0; r < NR2; ++r){
        int u = q - r;
        if (u >= 0 && u <= 50) acc[r] += wp[u]*v;
      }
    }
  }
}

// kC: per-phase-group partial conv -> outp[pgb][jo][c].
// Grid: 3130 blocks = 626 node-groups x 5 phase-groups (bijective XCD swizzle
// keeps adjacent node-groups on one XCD: 50/58-row window overlap -> L2 hits).
// Block = 4 waves, wave w = phase p = pgb*4+w; LDS-reduce 4 phases, write partial.
// Correction terms (mu, low) applied later in kC2.
__global__ __launch_bounds__(256, 3) void kC_conv(const float* __restrict__ x,
                                                  const int* __restrict__ sel,
                                                  const float* __restrict__ whigh,
                                                  float* __restrict__ outp){
  __shared__ float whs[1024];
  __shared__ f32x4 red[4][NR2][64];
  int tid = threadIdx.x;
  for (int i = tid; i < 1024; i += 256){
    int j = i - 1;                     // whs[i] = whT[i-1], zero-padded
    whs[i] = (j >= 0 && j < KH) ? whigh[WH_OFF + j] : 0.f;
  }
  // bijective XCD swizzle: NWG=3130, 8 XCDs, q=391, r=2
  int lin = blockIdx.x;
  int xcd = lin & 7, pos = lin >> 3;
  int wg  = (xcd < 2 ? xcd*392 : 784 + (xcd - 2)*391) + pos;
  int xg  = wg % NGX;                  // node-group (fast-varying -> same XCD contiguous)
  int pgb = wg / NGX;                  // phase-group
  int lane = tid & 63;
  int w    = tid >> 6;
  int p    = pgb*4 + w;                // this wave's phase
  int jo0  = xg * NR2;
  int m0   = jo0 - 26;
  int s0 = sel[4*lane+0], s1 = sel[4*lane+1], s2 = sel[4*lane+2], s3 = sel[4*lane+3];
  bool allc = __all((s0 == 4*lane) && (s1 == 4*lane+1) && (s2 == 4*lane+2) && (s3 == 4*lane+3));
  __syncthreads();
  float wp[51];
  #pragma unroll
  for (int u = 0; u < 51; ++u) wp[u] = whs[20*u + p];
  f32x4 acc[NR2];
  #pragma unroll
  for (int r = 0; r < NR2; ++r) acc[r] = f32x4{0.f, 0.f, 0.f, 0.f};
  if (m0 >= 0 && m0 + 57 < MLEN && allc)
       conv_core3<true >(x, wp, m0, p, lane, s0, s1, s2, s3, allc, acc);
  else conv_core3<false>(x, wp, m0, p, lane, s0, s1, s2, s3, allc, acc);
  #pragma unroll
  for (int r = 0; r < NR2; ++r) red[w][r][lane] = acc[r];
  __syncthreads();

  // epilogue: 32 threads per node row; each finishes 2 float4 (8 channels)
  int r  = tid >> 5;
  int jo = jo0 + r;
  if (jo < ND2E){
    #pragma unroll
    for (int k = 0; k < 2; ++k){
      int j = ((tid & 31) << 1) + k;   // float4 column 0..63
      f32x4 a = red[0][r][j] + red[1][r][j] + red[2][r][j] + red[3][r][j];
      *reinterpret_cast<f32x4*>(outp + ((size_t)pgb*ND2E + jo)*C_SEL + 4*j) = a;
    }
  }
}

// kC2: reduce the 5 phase-group partials and apply the mean/low correction:
// outd[jo] = sum_pg outp[pg][jo] + (mu - low(t_jo)) * s(t_jo)
// s = valid-window mass of the truncated kernel (exact zero-pad edge handling),
// low(t) ~ lerp(lowd) (G_high barely changes low: sigma ratio 20x).
__global__ __launch_bounds__(256) void kC_red(const float* __restrict__ outp,
                                              const float* __restrict__ cwh,
                                              const float* __restrict__ lowd,
                                              const float* __restrict__ musum,
                                              float* __restrict__ outd){
  int tid = threadIdx.x;
  int jo  = blockIdx.x*4 + (tid >> 6);
  int j   = tid & 63;                  // float4 column
  if (jo >= ND2E) return;
  f32x4 a = {0.f, 0.f, 0.f, 0.f};
  #pragma unroll
  for (int pg = 0; pg < NPG; ++pg)
    a += *reinterpret_cast<const f32x4*>(outp + ((size_t)pg*ND2E + jo)*C_SEL + 4*j);
  float mu = musum[0] * (1.0f/((float)T_LEN*(float)C_SEL));
  int tn = 20*(jo - 1);
  int jmin = 499 - tn;             if (jmin < 0) jmin = 0;
  int jmax = T_LEN - 1 + 499 - tn; if (jmax > 1000) jmax = 1000;
  float s = cwh[jmax + 1] - cwh[jmin];
  int tc = tn < 0 ? 0 : (tn > T_LEN-1 ? T_LEN-1 : tn);
  int jd = tc/50, rr = tc - 50*jd;
  float fr = rr*(1.f/50.f);
  f32x4 l0 = *reinterpret_cast<const f32x4*>(lowd + (size_t)jd*C_SEL + 4*j);
  f32x4 l1 = *reinterpret_cast<const f32x4*>(lowd + (size_t)(jd+1)*C_SEL + 4*j);
  f32x4 lo = l0 + (l1 - l0)*fr;
  *reinterpret_cast<f32x4*>(outd + (size_t)jo*C_SEL + 4*j) = a + (mu - lo)*s;
}

// kD: Catmull-Rom interpolation of the decimated output back to full rate.
__global__ __launch_bounds__(256) void kD_interp(const float* __restrict__ outd,
                                                 float* __restrict__ out){
  int c = threadIdx.x;
  int t0 = blockIdx.x*8;
  #pragma unroll
  for (int i = 0; i < 8; ++i){
    int t = t0 + i;
    int jo = t/20, rr = t - jo*20;
    float a = rr*(1.f/20.f);
    float p0 = outd[(jo    )*C_SEL + c];
    float p1 = outd[(jo + 1)*C_SEL + c];   // node at t = 20*jo
    float p2 = outd[(jo + 2)*C_SEL + c];   // node at t = 20*(jo+1)
    float p3 = outd[(jo + 3)*C_SEL + c];
    float m = p1 + 0.5f*a*((p2 - p0)
            + a*((2.f*p0 - 5.f*p1 + 4.f*p2 - p3)
            + a*(3.f*(p1 - p2) + p3 - p0)));
    out[(size_t)t*C_SEL + c] = m;
  }
}

extern "C" void kernel_launch(void* const* d_in, const int* in_sizes, int n_in,
                              void* d_out, int out_size, void* d_ws, size_t ws_size,
                              hipStream_t stream){
  const float* firings = (const float*)d_in[0];
  const float* glow    = (const float*)d_in[1];
  const float* ghigh   = (const float*)d_in[2];
  const int*   sel     = (const int*)d_in[3];
  float* out = (float*)d_out;
  float* ws  = (float*)d_ws;

  // workspace layout (floats): ~35 MB total
  float* W1    = ws;                 // 256
  float* musum = ws + 256;           // 64 (1 used)
  float* cwh   = ws + 320;           // 1002 (pad to 1728)
  float* S     = ws + 2048;          // 2000*256 = 512000   (ends 514048)
  float* lowd  = ws + 514048;        // 2001*256 = 512256   (ends 1026304)
  float* outd  = ws + 1026304;       // 5003*256 = 1280768  (ends 2307072)
  float* outp  = ws + 2307072;       // 5*5003*256 = 6403840 (ends 8710912)

  hipLaunchKernelGGL(kA_prep,  dim3(NB1+1),    dim3(256), 0, stream,
                     firings, sel, glow, ghigh, S, W1, musum, cwh);
  hipLaunchKernelGGL(kB_lowd,  dim3(ND1),      dim3(256), 0, stream, S, W1, lowd, musum);
  hipLaunchKernelGGL(kC_conv,  dim3(NWG),      dim3(256), 0, stream,
                     firings, sel, ghigh, outp);
  hipLaunchKernelGGL(kC_red,   dim3(1251),     dim3(256), 0, stream,
                     outp, cwh, lowd, musum, outd);
  hipLaunchKernelGGL(kD_interp,dim3(T_LEN/8),  dim3(256), 0, stream, outd, out);
}

// Round 4
// 450.856 us; speedup vs baseline: 1.2440x; 1.0689x over previous
//
#include <hip/hip_runtime.h>
#include <hip/hip_bf16.h>

#define T_LEN   100000   // time samples
#define C_SEL   256      // selected channels
#define C_IN    512      // input channel stride
#define KLOW    12000    // low-pass taps
#define B1      50       // low-pass decimation block
#define NB1     2000     // T_LEN / B1
#define ND1     2001     // low nodes: t = 50*jd, jd = 0..2000
#define NW1     241      // block-averaged low weights
#define ND2E    5003     // out nodes: t = 20*(jo-1), jo = 0..5002 (one extra each side for Catmull-Rom)
#define WH_OFF  5500     // gauss_high truncation start (center 6000 ± 500)
#define KH      1001     // truncated high-pass taps
#define NR2     8        // decimated outputs per node-group
#define NGX     626      // ceil(5003 / 8) node-group blocks
#define NPG     5        // phase-groups (4 phases each, one per wave)
#define NWG     (NGX*NPG) // 3130 kC blocks
#define MLEN    5000     // decimated length per phase (T_LEN/20)

typedef __attribute__((ext_vector_type(4))) float f32x4;

// kA: fused prep + block sums (vectorized, no packing).
//  blocks 0..NB1-1: S[jb][c] = 50-sample block sums of selected channels.
//    sel is arange(256) in practice -> channels are the contiguous first 1KB
//    of each 2KB row: float4 loads, full-row coalescing. Runtime-checked with
//    a gather fallback for safety.
//  block NB1: W1 (block-averaged low weights), musum=0, cwh = prefix of truncated high kernel.
__global__ __launch_bounds__(256) void kA_prep(const float* __restrict__ x,
                                               const int* __restrict__ sel,
                                               const float* __restrict__ wlow,
                                               const float* __restrict__ whigh,
                                               float* __restrict__ S,
                                               float* __restrict__ W1,
                                               float* __restrict__ musum,
                                               float* __restrict__ cwh){
  if (blockIdx.x < NB1){
    __shared__ f32x4 red[4][64];
    int jb = blockIdx.x;
    int tid = threadIdx.x;
    int c4 = tid & 63;          // float4 column (4 channels)
    int w  = tid >> 6;          // wave id: rows i = w, w+4, ...
    int s0 = sel[4*c4+0], s1 = sel[4*c4+1], s2 = sel[4*c4+2], s3 = sel[4*c4+3];
    bool contig = (s0 == 4*c4) && (s1 == 4*c4+1) && (s2 == 4*c4+2) && (s3 == 4*c4+3);
    bool allc = __all(contig);
    f32x4 acc = {0.f, 0.f, 0.f, 0.f};
    const float* rowb = x + (size_t)jb*(B1*C_IN);
    if (allc){
      for (int i = w; i < B1; i += 4)
        acc += *reinterpret_cast<const f32x4*>(rowb + (size_t)i*C_IN + 4*c4);
    } else {
      for (int i = w; i < B1; i += 4){
        const float* r = rowb + (size_t)i*C_IN;
        f32x4 v = { r[s0], r[s1], r[s2], r[s3] };
        acc += v;
      }
    }
    red[w][c4] = acc;
    __syncthreads();
    if (tid < 64){
      f32x4 s = red[0][tid] + red[1][tid] + red[2][tid] + red[3][tid];
      *reinterpret_cast<f32x4*>(S + (size_t)jb*C_SEL + 4*tid) = s;
    }
  } else {
    int m1 = threadIdx.x;
    if (m1 == 0){
      musum[0] = 0.f;
      float run = 0.f;
      cwh[0] = 0.f;
      for (int j = 0; j < KH; ++j){ run += whigh[WH_OFF + j]; cwh[j+1] = run; }
    }
    if (m1 < NW1){
      float s = 0.f;
      int kbase = 50*m1 - 1;
      for (int off = 0; off < 50; ++off){
        int k = kbase + off;
        if (k >= 0 && k < KLOW) s += wlow[k];
      }
      W1[m1] = s * (1.0f/50.0f);   // block MEAN weight × block SUM of x
    }
  }
}

// kB: decimated low-pass, vectorized: lowd[jd][c] = sum_m1 W1[m1]*S[jd+m1-120][c].
// 4 jd-nodes per block (one per wave); lane = f32x4 column; loop bounds hoisted
// (no per-iteration branch); musum via wave shfl reduce.
__global__ __launch_bounds__(256) void kB_lowd(const float* __restrict__ S,
                                               const float* __restrict__ W1,
                                               float* __restrict__ lowd,
                                               float* __restrict__ musum){
  __shared__ float w1s[NW1];
  int tid = threadIdx.x;
  if (tid < NW1) w1s[tid] = W1[tid];
  __syncthreads();
  int jd   = blockIdx.x*4 + (tid >> 6);
  int lane = tid & 63;
  if (jd >= ND1) return;
  int lo = 120 - jd;  if (lo < 0)   lo = 0;
  int hi = 2119 - jd; if (hi > 240) hi = 240;
  f32x4 acc = {0.f, 0.f, 0.f, 0.f};
  for (int m1 = lo; m1 <= hi; ++m1){
    int jb = jd + m1 - 120;
    acc += w1s[m1] * *reinterpret_cast<const f32x4*>(S + (size_t)jb*C_SEL + 4*lane);
  }
  *reinterpret_cast<f32x4*>(lowd + (size_t)jd*C_SEL + 4*lane) = acc;
  float t = acc.x + acc.y + acc.z + acc.w;
  for (int off = 32; off > 0; off >>= 1) t += __shfl_down(t, off);
  if (lane == 0){
    // sum_t lerp(low)[t] = 25.5*L[0] + 50*L[1..1999] + 24.5*L[2000]
    float ew = (jd == 0) ? 25.5f : ((jd == ND1-1) ? 24.5f : 50.f);
    atomicAdd(musum, ew*t);
  }
}

// kC core: for node jo, conv[jo] = sum_{j=0..1000} whT[j] * xsel[20*(jo-1)+j-499].
// Phase decomposition t = 20m+p: tap index j = 20u+p-1, u = m-jo+26 in [0,50];
// whs is the +1-shifted zero-padded kernel so tap(u) = whs[20u+p].
// REGISTER-PRESSURE FIX vs previous version: the 8 accumulators at step q only
// need taps u = q-7..q -> sliding ring wr[8] fed by ONE broadcast ds_read per q
// (wave-uniform addr), instead of a 51-entry register array. Freed VGPRs fund an
// explicit 8-deep f32x4 prefetch ring for the x rows (addresses known upfront),
// so the 58 strided 1KB loads pipeline instead of serializing at HBM latency.
template<bool FAST>
__device__ __forceinline__ void conv_core4(const float* __restrict__ x,
                                           const float* __restrict__ whs,
                                           int m0, int p, int lane,
                                           int s0, int s1, int s2, int s3,
                                           bool allc, f32x4* acc){
  float wr[8];
  if (FAST){
    const float* base = x + (size_t)(20*m0 + p)*C_IN + 4*lane;
    f32x4 vb[8];
    #pragma unroll
    for (int q = 0; q < 8; ++q)
      vb[q] = *reinterpret_cast<const f32x4*>(base + (size_t)q*(20*C_IN));
    #pragma unroll
    for (int q = 0; q < 58; ++q){
      wr[q & 7] = (q <= 50) ? whs[20*q + p] : 0.f;   // u=q enters; u=q-8 retires
      f32x4 v = vb[q & 7];
      if (q + 8 < 58)
        vb[q & 7] = *reinterpret_cast<const f32x4*>(base + (size_t)(q+8)*(20*C_IN));
      #pragma unroll
      for (int r = 0; r < NR2; ++r){
        int u = q - r;
        if (u >= 0 && u <= 50) acc[r] += wr[u & 7]*v;  // all indices static after unroll
      }
    }
  } else {
    #pragma unroll
    for (int q = 0; q < 58; ++q){
      int m = m0 + q;
      f32x4 v = {0.f, 0.f, 0.f, 0.f};
      if (m >= 0 && m < MLEN){
        const float* row = x + (size_t)(20*m + p)*C_IN;
        if (allc) v = *reinterpret_cast<const f32x4*>(row + 4*lane);
        else      v = f32x4{ row[s0], row[s1], row[s2], row[s3] };
      }
      wr[q & 7] = (q <= 50) ? whs[20*q + p] : 0.f;
      #pragma unroll
      for (int r = 0; r < NR2; ++r){
        int u = q - r;
        if (u >= 0 && u <= 50) acc[r] += wr[u & 7]*v;
      }
    }
  }
}

// kC: per-phase-group partial conv -> outp[pgb][jo][c].
// Grid: 3130 blocks = 626 node-groups x 5 phase-groups (bijective XCD swizzle
// keeps adjacent node-groups on one XCD: 50/58-row window overlap -> L2 hits).
// Block = 4 waves, wave w = phase p = pgb*4+w; LDS-reduce 4 phases, write partial.
// No min-waves launch-bound: occupancy is LDS-capped (36KB -> 4 blocks/CU); the
// allocator must NOT be starved below the ~90-reg live set (R1 lesson).
__global__ __launch_bounds__(256) void kC_conv(const float* __restrict__ x,
                                               const int* __restrict__ sel,
                                               const float* __restrict__ whigh,
                                               float* __restrict__ outp){
  __shared__ float whs[1024];
  __shared__ f32x4 red[4][NR2][64];
  int tid = threadIdx.x;
  for (int i = tid; i < 1024; i += 256){
    int j = i - 1;                     // whs[i] = whT[i-1], zero-padded
    whs[i] = (j >= 0 && j < KH) ? whigh[WH_OFF + j] : 0.f;
  }
  // bijective XCD swizzle: NWG=3130, 8 XCDs, q=391, r=2
  int lin = blockIdx.x;
  int xcd = lin & 7, pos = lin >> 3;
  int wg  = (xcd < 2 ? xcd*392 : 784 + (xcd - 2)*391) + pos;
  int xg  = wg % NGX;                  // node-group (fast-varying -> same XCD contiguous)
  int pgb = wg / NGX;                  // phase-group
  int lane = tid & 63;
  int w    = tid >> 6;
  int p    = pgb*4 + w;                // this wave's phase
  int jo0  = xg * NR2;
  int m0   = jo0 - 26;
  int s0 = sel[4*lane+0], s1 = sel[4*lane+1], s2 = sel[4*lane+2], s3 = sel[4*lane+3];
  bool allc = __all((s0 == 4*lane) && (s1 == 4*lane+1) && (s2 == 4*lane+2) && (s3 == 4*lane+3));
  __syncthreads();
  f32x4 acc[NR2];
  #pragma unroll
  for (int r = 0; r < NR2; ++r) acc[r] = f32x4{0.f, 0.f, 0.f, 0.f};
  if (m0 >= 0 && m0 + 57 < MLEN && allc)
       conv_core4<true >(x, whs, m0, p, lane, s0, s1, s2, s3, allc, acc);
  else conv_core4<false>(x, whs, m0, p, lane, s0, s1, s2, s3, allc, acc);
  #pragma unroll
  for (int r = 0; r < NR2; ++r) red[w][r][lane] = acc[r];
  __syncthreads();

  // epilogue: 32 threads per node row; each finishes 2 float4 (8 channels)
  int r  = tid >> 5;
  int jo = jo0 + r;
  if (jo < ND2E){
    #pragma unroll
    for (int k = 0; k < 2; ++k){
      int j = ((tid & 31) << 1) + k;   // float4 column 0..63
      f32x4 a = red[0][r][j] + red[1][r][j] + red[2][r][j] + red[3][r][j];
      *reinterpret_cast<f32x4*>(outp + ((size_t)pgb*ND2E + jo)*C_SEL + 4*j) = a;
    }
  }
}

// kC2: reduce the 5 phase-group partials and apply the mean/low correction:
// outd[jo] = sum_pg outp[pg][jo] + (mu - low(t_jo)) * s(t_jo)
// s = valid-window mass of the truncated kernel (exact zero-pad edge handling),
// low(t) ~ lerp(lowd) (G_high barely changes low: sigma ratio 20x).
__global__ __launch_bounds__(256) void kC_red(const float* __restrict__ outp,
                                              const float* __restrict__ cwh,
                                              const float* __restrict__ lowd,
                                              const float* __restrict__ musum,
                                              float* __restrict__ outd){
  int tid = threadIdx.x;
  int jo  = blockIdx.x*4 + (tid >> 6);
  int j   = tid & 63;                  // float4 column
  if (jo >= ND2E) return;
  f32x4 a = {0.f, 0.f, 0.f, 0.f};
  #pragma unroll
  for (int pg = 0; pg < NPG; ++pg)
    a += *reinterpret_cast<const f32x4*>(outp + ((size_t)pg*ND2E + jo)*C_SEL + 4*j);
  float mu = musum[0] * (1.0f/((float)T_LEN*(float)C_SEL));
  int tn = 20*(jo - 1);
  int jmin = 499 - tn;             if (jmin < 0) jmin = 0;
  int jmax = T_LEN - 1 + 499 - tn; if (jmax > 1000) jmax = 1000;
  float s = cwh[jmax + 1] - cwh[jmin];
  int tc = tn < 0 ? 0 : (tn > T_LEN-1 ? T_LEN-1 : tn);
  int jd = tc/50, rr = tc - 50*jd;
  float fr = rr*(1.f/50.f);
  f32x4 l0 = *reinterpret_cast<const f32x4*>(lowd + (size_t)jd*C_SEL + 4*j);
  f32x4 l1 = *reinterpret_cast<const f32x4*>(lowd + (size_t)(jd+1)*C_SEL + 4*j);
  f32x4 lo = l0 + (l1 - l0)*fr;
  *reinterpret_cast<f32x4*>(outd + (size_t)jo*C_SEL + 4*j) = a + (mu - lo)*s;
}

// kD: Catmull-Rom interpolation back to full rate, vectorized: lane = f32x4
// column, wave handles full 1KB output rows (store_dwordx4 x 64 lanes/row).
__global__ __launch_bounds__(256) void kD_interp(const float* __restrict__ outd,
                                                 float* __restrict__ out){
  int tid  = threadIdx.x;
  int lane = tid & 63;
  int w    = tid >> 6;
  int t0   = blockIdx.x*8;
  #pragma unroll
  for (int k = 0; k < 2; ++k){
    int t = t0 + w + 4*k;
    int jo = t/20, rr = t - jo*20;
    float a = rr*(1.f/20.f);
    const float* b = outd + (size_t)jo*C_SEL + 4*lane;
    f32x4 p0 = *reinterpret_cast<const f32x4*>(b);
    f32x4 p1 = *reinterpret_cast<const f32x4*>(b +   C_SEL);  // node at t = 20*jo
    f32x4 p2 = *reinterpret_cast<const f32x4*>(b + 2*C_SEL);  // node at t = 20*(jo+1)
    f32x4 p3 = *reinterpret_cast<const f32x4*>(b + 3*C_SEL);
    f32x4 m = p1 + 0.5f*a*((p2 - p0)
            + a*((2.f*p0 - 5.f*p1 + 4.f*p2 - p3)
            + a*(3.f*(p1 - p2) + p3 - p0)));
    *reinterpret_cast<f32x4*>(out + (size_t)t*C_SEL + 4*lane) = m;
  }
}

extern "C" void kernel_launch(void* const* d_in, const int* in_sizes, int n_in,
                              void* d_out, int out_size, void* d_ws, size_t ws_size,
                              hipStream_t stream){
  const float* firings = (const float*)d_in[0];
  const float* glow    = (const float*)d_in[1];
  const float* ghigh   = (const float*)d_in[2];
  const int*   sel     = (const int*)d_in[3];
  float* out = (float*)d_out;
  float* ws  = (float*)d_ws;

  // workspace layout (floats): ~35 MB total
  float* W1    = ws;                 // 256
  float* musum = ws + 256;           // 64 (1 used)
  float* cwh   = ws + 320;           // 1002 (pad to 1728)
  float* S     = ws + 2048;          // 2000*256 = 512000   (ends 514048)
  float* lowd  = ws + 514048;        // 2001*256 = 512256   (ends 1026304)
  float* outd  = ws + 1026304;       // 5003*256 = 1280768  (ends 2307072)
  float* outp  = ws + 2307072;       // 5*5003*256 = 6403840 (ends 8710912)

  hipLaunchKernelGGL(kA_prep,  dim3(NB1+1),    dim3(256), 0, stream,
                     firings, sel, glow, ghigh, S, W1, musum, cwh);
  hipLaunchKernelGGL(kB_lowd,  dim3(501),      dim3(256), 0, stream, S, W1, lowd, musum);
  hipLaunchKernelGGL(kC_conv,  dim3(NWG),      dim3(256), 0, stream,
                     firings, sel, ghigh, outp);
  hipLaunchKernelGGL(kC_red,   dim3(1251),     dim3(256), 0, stream,
                     outp, cwh, lowd, musum, outd);
  hipLaunchKernelGGL(kD_interp,dim3(T_LEN/8),  dim3(256), 0, stream, outd, out);
}